// Round 4
// baseline (502.322 us; speedup 1.0000x reference)
//
#include <hip/hip_runtime.h>

#define T_STEPS 8

// IF-neuron recurrence over T=8 steps, independent per spatial element.
// Memory-bound: 9 x 16B loads + 9 x 16B stores per thread, coalesced.
// Floor: 604 MB @ ~6.45 TB/s (measured on this part) ~= 94 us.
//
// NUMERICS: comparator is a float64 numpy ground truth with a {-1,0,+1}
// output; we integrate in f64 (round 2: passed, absmax 0.0).
// Round 3/4 change: replace IEEE f64 division /(t+1) with multiply by the
// precomputed reciprocal.
//  - eout path: spike in {-1,0,+1} and th==1.0, so s*nearest(1/n) is
//    BIT-IDENTICAL to nearest(s/n).
//  - ein path: product differs from the correctly-rounded quotient by
//    <=1 ulp (2^-52 rel); a spike flips only if mem lands within ~1e-15
//    of the boundary -> expected flips over 1.3e8 comparisons ~1e-7.
// Round 4 fix: __builtin_nontemporal_store needs a NATIVE vector type,
// not HIP's float4 class -> use ext_vector_type(4).

typedef float vfloat4 __attribute__((ext_vector_type(4)));

__global__ __launch_bounds__(256) void if_diff_kernel(
    const vfloat4* __restrict__ x,
    const float* __restrict__ thresh_p,
    vfloat4* __restrict__ out,
    int n4)
{
    int i = blockIdx.x * blockDim.x + threadIdx.x;
    if (i >= n4) return;

    const double th = (double)thresh_p[0];

    // Correctly-rounded double reciprocals of 1..8 (compile-time exact).
    const double inv_t[T_STEPS] = {
        1.0, 0.5, 1.0 / 3.0, 0.25, 0.2, 1.0 / 6.0, 1.0 / 7.0, 0.125
    };

    // x0 = first temporal slice
    vfloat4 x0v = x[i];
    double x0[4] = {(double)x0v.x, (double)x0v.y, (double)x0v.z, (double)x0v.w};

    // output slice 0 is all zeros (harness poisons d_out, so write it)
    vfloat4 zero4 = {0.f, 0.f, 0.f, 0.f};
    __builtin_nontemporal_store(zero4, &out[i]);

    double mem[4], ein[4], eout[4];
    #pragma unroll
    for (int c = 0; c < 4; ++c) { mem[c] = 0.5 * th; ein[c] = 0.0; eout[c] = 0.0; }

    #pragma unroll
    for (int t = 0; t < T_STEPS; ++t) {
        const double inv = inv_t[t];
        vfloat4 xv = x[(size_t)(t + 1) * (size_t)n4 + (size_t)i];
        double xt[4] = {(double)xv.x, (double)xv.y, (double)xv.z, (double)xv.w};
        vfloat4 sp;
        #pragma unroll
        for (int c = 0; c < 4; ++c) {
            // mem = mem + xt + exp_in - exp_out   (reference assoc order)
            double m = ((mem[c] + xt[c]) + ein[c]) - eout[c];
            // spike = zif(m - th)*th - zif(-m)*th ; zif(u) = (u >= 0)
            double s = ((m - th) >= 0.0 ? th : 0.0) - ((-m) >= 0.0 ? th : 0.0);
            m = m - s;
            ein[c]  = ein[c]  + (xt[c] - x0[c]) * inv;
            eout[c] = eout[c] + s * inv;
            mem[c] = m;
            sp[c] = (float)s;
        }
        __builtin_nontemporal_store(
            sp, &out[(size_t)(t + 1) * (size_t)n4 + (size_t)i]);
    }
}

extern "C" void kernel_launch(void* const* d_in, const int* in_sizes, int n_in,
                              void* d_out, int out_size, void* d_ws, size_t ws_size,
                              hipStream_t stream) {
    const float* x      = (const float*)d_in[0];
    const float* thresh = (const float*)d_in[1];
    float* out          = (float*)d_out;

    const int N  = in_sizes[0] / (T_STEPS + 1);  // elements per temporal slice
    const int n4 = N / 4;                        // float4 groups per slice

    const int block = 256;
    const int grid  = (n4 + block - 1) / block;
    if_diff_kernel<<<grid, block, 0, stream>>>(
        (const vfloat4*)x, thresh, (vfloat4*)out, n4);
}

// Round 5
// 483.411 us; speedup vs baseline: 1.0391x; 1.0391x over previous
//
#include <hip/hip_runtime.h>

#define T_STEPS 8

// IF-neuron recurrence over T=8 steps, independent per spatial element.
// Memory-bound: 9 x 16B loads + 9 x 16B stores per thread, coalesced.
// Floor: 604 MB @ ~6.45 TB/s (measured via harness fills) ~= 94 us.
// Kernel dispatch is < 184 us (absent from rocprof top-5); dur_us ~500 is
// dominated by harness restore/poison fills (~2 x 186 us).
//
// NUMERICS: comparator is a float64 numpy ground truth with a {-1,0,+1}
// output; we integrate in f64 (round 2: passed, absmax 0.0).
// /(t+1) replaced by multiply with the correctly-rounded reciprocal:
//  - eout path: spike in {-1,0,+1} and th==1.0 -> BIT-IDENTICAL.
//  - ein path: <=1 ulp off the true quotient; spike flips need mem within
//    ~1e-15 of the boundary -> expected flips over 1.3e8 comparisons ~1e-7.
// Round 5 change: revert nontemporal stores (round 4: 487->502 us; nt
// bypasses L2/L3 write buffering for zero benefit on a must-drain stream).

typedef float vfloat4 __attribute__((ext_vector_type(4)));

__global__ __launch_bounds__(256) void if_diff_kernel(
    const vfloat4* __restrict__ x,
    const float* __restrict__ thresh_p,
    vfloat4* __restrict__ out,
    int n4)
{
    int i = blockIdx.x * blockDim.x + threadIdx.x;
    if (i >= n4) return;

    const double th = (double)thresh_p[0];

    // Correctly-rounded double reciprocals of 1..8 (compile-time exact).
    const double inv_t[T_STEPS] = {
        1.0, 0.5, 1.0 / 3.0, 0.25, 0.2, 1.0 / 6.0, 1.0 / 7.0, 0.125
    };

    // x0 = first temporal slice
    vfloat4 x0v = x[i];
    double x0[4] = {(double)x0v.x, (double)x0v.y, (double)x0v.z, (double)x0v.w};

    // output slice 0 is all zeros (harness poisons d_out, so write it)
    vfloat4 zero4 = {0.f, 0.f, 0.f, 0.f};
    out[i] = zero4;

    double mem[4], ein[4], eout[4];
    #pragma unroll
    for (int c = 0; c < 4; ++c) { mem[c] = 0.5 * th; ein[c] = 0.0; eout[c] = 0.0; }

    #pragma unroll
    for (int t = 0; t < T_STEPS; ++t) {
        const double inv = inv_t[t];
        vfloat4 xv = x[(size_t)(t + 1) * (size_t)n4 + (size_t)i];
        double xt[4] = {(double)xv.x, (double)xv.y, (double)xv.z, (double)xv.w};
        vfloat4 sp;
        #pragma unroll
        for (int c = 0; c < 4; ++c) {
            // mem = mem + xt + exp_in - exp_out   (reference assoc order)
            double m = ((mem[c] + xt[c]) + ein[c]) - eout[c];
            // spike = zif(m - th)*th - zif(-m)*th ; zif(u) = (u >= 0)
            double s = ((m - th) >= 0.0 ? th : 0.0) - ((-m) >= 0.0 ? th : 0.0);
            m = m - s;
            ein[c]  = ein[c]  + (xt[c] - x0[c]) * inv;
            eout[c] = eout[c] + s * inv;
            mem[c] = m;
            sp[c] = (float)s;
        }
        out[(size_t)(t + 1) * (size_t)n4 + (size_t)i] = sp;
    }
}

extern "C" void kernel_launch(void* const* d_in, const int* in_sizes, int n_in,
                              void* d_out, int out_size, void* d_ws, size_t ws_size,
                              hipStream_t stream) {
    const float* x      = (const float*)d_in[0];
    const float* thresh = (const float*)d_in[1];
    float* out          = (float*)d_out;

    const int N  = in_sizes[0] / (T_STEPS + 1);  // elements per temporal slice
    const int n4 = N / 4;                        // float4 groups per slice

    const int block = 256;
    const int grid  = (n4 + block - 1) / block;
    if_diff_kernel<<<grid, block, 0, stream>>>(
        (const vfloat4*)x, thresh, (vfloat4*)out, n4);
}